// Round 12
// baseline (1466.150 us; speedup 1.0000x reference)
//
#include <hip/hip_runtime.h>
#include <stdint.h>

#define N_GENES 16384
#define Z_DIM   1024
#define D_K     128
#define N_CELLS 4096

typedef __attribute__((ext_vector_type(8))) short bf16x8;
typedef __attribute__((ext_vector_type(4))) float f32x4;

// ---------------------------------------------------------------------------
// JAX threefry2x32 (20 rounds) — verified variant: partitionable, bits1^bits2
// ---------------------------------------------------------------------------
__device__ __forceinline__ uint32_t rotl32(uint32_t x, int r) {
  return (x << r) | (x >> (32 - r));
}

__device__ __forceinline__ void threefry2x32(uint32_t k0, uint32_t k1,
                                             uint32_t& x0, uint32_t& x1) {
  const uint32_t ks2 = k0 ^ k1 ^ 0x1BD11BDAu;
  x0 += k0; x1 += k1;
#define TF_ROUND(r) { x0 += x1; x1 = rotl32(x1, (r)); x1 ^= x0; }
  TF_ROUND(13) TF_ROUND(15) TF_ROUND(26) TF_ROUND(6)
  x0 += k1;  x1 += ks2 + 1u;
  TF_ROUND(17) TF_ROUND(29) TF_ROUND(16) TF_ROUND(24)
  x0 += ks2; x1 += k0 + 2u;
  TF_ROUND(13) TF_ROUND(15) TF_ROUND(26) TF_ROUND(6)
  x0 += k0;  x1 += k1 + 3u;
  TF_ROUND(17) TF_ROUND(29) TF_ROUND(16) TF_ROUND(24)
  x0 += k1;  x1 += ks2 + 4u;
  TF_ROUND(13) TF_ROUND(15) TF_ROUND(26) TF_ROUND(6)
  x0 += ks2; x1 += k0 + 5u;
#undef TF_ROUND
}

__device__ __forceinline__ float gumbel_from(uint32_t n) {
  uint32_t x0 = 0u, x1 = n;   // counter = (hi, lo) of uint64 flat index
  threefry2x32(0u, 42u, x0, x1);
  uint32_t bits = x0 ^ x1;    // partitionable sub-64-bit fold  (R3-verified)
  float f = __uint_as_float((bits >> 9) | 0x3F800000u) - 1.0f;
  const float tiny = 1.17549435082228751e-38f;
  float u = fmaxf(tiny, f + tiny);
  return -logf(-logf(u));
}

__device__ __forceinline__ ushort f32_to_bf16(float x) {
  uint32_t u = __float_as_uint(x);
  uint32_t r = (u + 0x7FFFu + ((u >> 16) & 1u)) >> 16;  // RNE
  return (ushort)r;
}

__device__ __forceinline__ float bf16_to_f32(ushort h) {
  return __uint_as_float(((uint32_t)h) << 16);
}

__device__ __forceinline__ void gload_lds16(const void* g, void* l) {
  __builtin_amdgcn_global_load_lds(
      (const __attribute__((address_space(1))) unsigned int*)g,
      (__attribute__((address_space(3))) unsigned int*)l, 16, 0, 0);
}

// ---------------------------------------------------------------------------
// Kernel P: fused prep (R8-retained). Blocks [0, NB_HILO) do hi/lo split of
// Q then K; blocks [NB_HILO, +1024) transpose+convert V -> Vt bf16.
// ---------------------------------------------------------------------------
#define HILO_Q_N4 (N_GENES * D_K / 4)            // 524288
#define HILO_K_N4 (Z_DIM * D_K / 4)              // 32768
#define NB_HILO   ((HILO_Q_N4 + HILO_K_N4) / 256)  // 2176

__global__ __launch_bounds__(256) void prep_kernel(
    const float* __restrict__ Q, const float* __restrict__ K,
    const float* __restrict__ V,
    ushort* __restrict__ Qh, ushort* __restrict__ Ql,
    ushort* __restrict__ Kh, ushort* __restrict__ Kl,
    ushort* __restrict__ Vt) {
  const int b = blockIdx.x;
  const int t = threadIdx.x;

  if (b < NB_HILO) {
    int i = b * 256 + t;
    const float* src; ushort* hi; ushort* lo;
    if (i < HILO_Q_N4) { src = Q; hi = Qh; lo = Ql; }
    else { i -= HILO_Q_N4; src = K; hi = Kh; lo = Kl; }
    float4 v = ((const float4*)src)[i];
    ushort4 h, l;
    h.x = f32_to_bf16(v.x); l.x = f32_to_bf16(v.x - bf16_to_f32(h.x));
    h.y = f32_to_bf16(v.y); l.y = f32_to_bf16(v.y - bf16_to_f32(h.y));
    h.z = f32_to_bf16(v.z); l.z = f32_to_bf16(v.z - bf16_to_f32(h.z));
    h.w = f32_to_bf16(v.w); l.w = f32_to_bf16(v.w - bf16_to_f32(h.w));
    ((ushort4*)hi)[i] = h;
    ((ushort4*)lo)[i] = l;
    return;
  }

  // V transpose: vb in [0, 1024) -> 64x64 tile
  __shared__ ushort tile[64][68];
  const int vb = b - NB_HILO;
  const int n0 = (vb & 63) * 64;   // cell block
  const int k0 = (vb >> 6) * 64;   // z block

  #pragma unroll
  for (int j = 0; j < 4; ++j) {
    int e = j * 1024 + t * 4;
    int r = e >> 6, c = e & 63;
    float4 v = *(const float4*)&V[(size_t)(k0 + r) * N_CELLS + n0 + c];
    tile[r][c + 0] = f32_to_bf16(v.x);
    tile[r][c + 1] = f32_to_bf16(v.y);
    tile[r][c + 2] = f32_to_bf16(v.z);
    tile[r][c + 3] = f32_to_bf16(v.w);
  }
  __syncthreads();
  #pragma unroll
  for (int j = 0; j < 4; ++j) {
    int u = j * 256 + t;
    int n = u >> 4, kb = (u & 15) * 4;
    ushort4 o;
    o.x = tile[kb + 0][n]; o.y = tile[kb + 1][n];
    o.z = tile[kb + 2][n]; o.w = tile[kb + 3][n];
    *(ushort4*)&Vt[(size_t)(n0 + n) * Z_DIM + k0 + kb] = o;
  }
}

// ---------------------------------------------------------------------------
// Kernel A (MFMA): scores via split-bf16 3-pass MFMA + gumbel-softmax.
// (R7-verified) 16 genes/block, 4 waves; K chunks double-buffered, swizzled.
// ---------------------------------------------------------------------------
__global__ __launch_bounds__(256) void attn_mfma_kernel(
    const ushort* __restrict__ Qh, const ushort* __restrict__ Ql,
    const ushort* __restrict__ Kh, const ushort* __restrict__ Kl,
    float* __restrict__ P, ushort* __restrict__ Pb) {
  __shared__ __attribute__((aligned(16))) ushort qsm[2][16][128];      // [h/l]
  __shared__ __attribute__((aligned(16))) ushort ksm[2][2][64][128];   // [buf][h/l]
  __shared__ float redmax[4][16];
  __shared__ float redsum[4][16];

  const int t    = threadIdx.x;
  const int g0   = blockIdx.x * 16;
  const int wave = t >> 6, lane = t & 63;
  const int fr   = lane & 15, lhi = lane >> 4;

  {
    int un = t, row = un >> 4, usrc = (un & 15) ^ (row & 7);
    gload_lds16(Qh + (size_t)(g0 + row) * D_K + usrc * 8, &qsm[0][0][0] + un * 8);
    gload_lds16(Ql + (size_t)(g0 + row) * D_K + usrc * 8, &qsm[1][0][0] + un * 8);
  }

#define KSTAGE(buf, zc) do {                                                  \
    _Pragma("unroll") for (int j_ = 0; j_ < 4; ++j_) {                        \
      int un_ = j_ * 256 + t, row_ = un_ >> 4;                                \
      int us_ = (un_ & 15) ^ (row_ & 7);                                      \
      gload_lds16(Kh + (size_t)((zc) + row_) * D_K + us_ * 8,                 \
                  &ksm[buf][0][0][0] + un_ * 8);                              \
      gload_lds16(Kl + (size_t)((zc) + row_) * D_K + us_ * 8,                 \
                  &ksm[buf][1][0][0] + un_ * 8);                              \
    } } while (0)

  KSTAGE(0, 0);
  __syncthreads();

  bf16x8 ah[4], al[4];
  #pragma unroll
  for (int ks = 0; ks < 4; ++ks) {
    int q = (ks * 4 + lhi) ^ (fr & 7);
    ah[ks] = *(const bf16x8*)(&qsm[0][fr][0] + q * 8);
    al[ks] = *(const bf16x8*)(&qsm[1][fr][0] + q * 8);
  }

  f32x4 acc[16] = {};
  const int rowk = wave * 16 + fr;

  #pragma unroll
  for (int c = 0; c < 16; ++c) {
    if (c < 15) KSTAGE((c + 1) & 1, (c + 1) * 64);
    const ushort* kbh = &ksm[c & 1][0][0][0];
    const ushort* kbl = &ksm[c & 1][1][0][0];
    #pragma unroll
    for (int ks = 0; ks < 4; ++ks) {
      int q = (ks * 4 + lhi) ^ (fr & 7);
      bf16x8 bh = *(const bf16x8*)(kbh + rowk * 128 + q * 8);
      bf16x8 bl = *(const bf16x8*)(kbl + rowk * 128 + q * 8);
      acc[c] = __builtin_amdgcn_mfma_f32_16x16x32_bf16(ah[ks], bh, acc[c], 0, 0, 0);
      acc[c] = __builtin_amdgcn_mfma_f32_16x16x32_bf16(ah[ks], bl, acc[c], 0, 0, 0);
      acc[c] = __builtin_amdgcn_mfma_f32_16x16x32_bf16(al[ks], bh, acc[c], 0, 0, 0);
    }
    __syncthreads();
  }
#undef KSTAGE

  const float scale = 0.08838834764831845f;  // 1/sqrt(128)

  #pragma unroll
  for (int c = 0; c < 16; ++c) {
    #pragma unroll
    for (int r = 0; r < 4; ++r) {
      uint32_t gene = (uint32_t)(g0 + lhi * 4 + r);
      uint32_t z    = (uint32_t)(c * 64 + wave * 16 + fr);
      acc[c][r] = fmaf(acc[c][r], scale, gumbel_from(gene * (uint32_t)Z_DIM + z));
    }
  }

  float m[4] = {-INFINITY, -INFINITY, -INFINITY, -INFINITY};
  #pragma unroll
  for (int c = 0; c < 16; ++c)
    #pragma unroll
    for (int r = 0; r < 4; ++r) m[r] = fmaxf(m[r], acc[c][r]);
  #pragma unroll
  for (int off = 1; off <= 8; off <<= 1)
    #pragma unroll
    for (int r = 0; r < 4; ++r) m[r] = fmaxf(m[r], __shfl_xor(m[r], off));
  if (fr == 0) {
    #pragma unroll
    for (int r = 0; r < 4; ++r) redmax[wave][lhi * 4 + r] = m[r];
  }
  __syncthreads();
  #pragma unroll
  for (int r = 0; r < 4; ++r) {
    int g = lhi * 4 + r;
    m[r] = fmaxf(fmaxf(redmax[0][g], redmax[1][g]),
                 fmaxf(redmax[2][g], redmax[3][g]));
  }

  float sum[4] = {0.f, 0.f, 0.f, 0.f};
  #pragma unroll
  for (int c = 0; c < 16; ++c)
    #pragma unroll
    for (int r = 0; r < 4; ++r) {
      acc[c][r] = expf(acc[c][r] - m[r]);
      sum[r] += acc[c][r];
    }
  #pragma unroll
  for (int off = 1; off <= 8; off <<= 1)
    #pragma unroll
    for (int r = 0; r < 4; ++r) sum[r] += __shfl_xor(sum[r], off);
  if (fr == 0) {
    #pragma unroll
    for (int r = 0; r < 4; ++r) redsum[wave][lhi * 4 + r] = sum[r];
  }
  __syncthreads();
  float inv[4];
  #pragma unroll
  for (int r = 0; r < 4; ++r) {
    int g = lhi * 4 + r;
    inv[r] = 1.0f / (redsum[0][g] + redsum[1][g] + redsum[2][g] + redsum[3][g]);
  }

  #pragma unroll
  for (int c = 0; c < 16; ++c)
    #pragma unroll
    for (int r = 0; r < 4; ++r) {
      float p = acc[c][r] * inv[r];
      size_t idx = (size_t)(g0 + lhi * 4 + r) * Z_DIM + c * 64 + wave * 16 + fr;
      P[idx] = p;
      Pb[idx] = f32_to_bf16(p);
    }
}

// ---------------------------------------------------------------------------
// Kernel A-fallback (f32 VALU, R3-verified) — used only if ws too small.
// ---------------------------------------------------------------------------
__global__ __launch_bounds__(256) void attn_p_kernel(
    const float* __restrict__ Q, const float* __restrict__ K,
    float* __restrict__ P, ushort* __restrict__ Pb) {
  __shared__ float  qs[8][128];
  __shared__ float4 kk4[64][32];

  const int t    = threadIdx.x;
  const int g0   = blockIdx.x * 8;
  const int wave = t >> 6, lane = t & 63;

  {
    int r = t / 32, c4 = t % 32;
    *(float4*)&qs[r][c4 * 4] =
        *(const float4*)&Q[(size_t)(g0 + r) * D_K + c4 * 4];
  }

  const int r0 = wave * 2, r1 = wave * 2 + 1;
  float sA[16], sB[16];

  for (int c = 0; c < 16; ++c) {
    const int zc = c * 64;
    __syncthreads();
    #pragma unroll
    for (int i = 0; i < 8; ++i) {
      int fidx = t + 256 * i;
      int zr = fidx / 32, c4 = fidx % 32;
      float4 v = *(const float4*)&K[(size_t)(zc + zr) * D_K + c4 * 4];
      kk4[zr][c4 ^ (zr & 31)] = v;
    }
    __syncthreads();
    float s0 = 0.f, s1 = 0.f;
    #pragma unroll
    for (int d4 = 0; d4 < 32; ++d4) {
      float4 kv = kk4[lane][d4 ^ (lane & 31)];
      float4 q0 = *(const float4*)&qs[r0][d4 * 4];
      float4 q1 = *(const float4*)&qs[r1][d4 * 4];
      s0 = fmaf(q0.x, kv.x, s0); s0 = fmaf(q0.y, kv.y, s0);
      s0 = fmaf(q0.z, kv.z, s0); s0 = fmaf(q0.w, kv.w, s0);
      s1 = fmaf(q1.x, kv.x, s1); s1 = fmaf(q1.y, kv.y, s1);
      s1 = fmaf(q1.z, kv.z, s1); s1 = fmaf(q1.w, kv.w, s1);
    }
    sA[c] = s0; sB[c] = s1;
  }

  const float scale = 0.08838834764831845f;

  {
    float s[16]; float mx = -INFINITY;
    #pragma unroll
    for (int i = 0; i < 16; ++i) {
      uint32_t n = (uint32_t)((g0 + r0) * Z_DIM + 64 * i + lane);
      s[i] = fmaf(sA[i], scale, gumbel_from(n));
      mx = fmaxf(mx, s[i]);
    }
    #pragma unroll
    for (int off = 32; off; off >>= 1) mx = fmaxf(mx, __shfl_xor(mx, off));
    float sum = 0.f;
    #pragma unroll
    for (int i = 0; i < 16; ++i) { s[i] = expf(s[i] - mx); sum += s[i]; }
    #pragma unroll
    for (int off = 32; off; off >>= 1) sum += __shfl_xor(sum, off);
    #pragma unroll
    for (int i = 0; i < 16; ++i) {
      size_t idx = (size_t)(g0 + r0) * Z_DIM + 64 * i + lane;
      float p = s[i] / sum;
      P[idx] = p;
      if (Pb) Pb[idx] = f32_to_bf16(p);
    }
  }
  {
    float s[16]; float mx = -INFINITY;
    #pragma unroll
    for (int i = 0; i < 16; ++i) {
      uint32_t n = (uint32_t)((g0 + r1) * Z_DIM + 64 * i + lane);
      s[i] = fmaf(sB[i], scale, gumbel_from(n));
      mx = fmaxf(mx, s[i]);
    }
    #pragma unroll
    for (int off = 32; off; off >>= 1) mx = fmaxf(mx, __shfl_xor(mx, off));
    float sum = 0.f;
    #pragma unroll
    for (int i = 0; i < 16; ++i) { s[i] = expf(s[i] - mx); sum += s[i]; }
    #pragma unroll
    for (int off = 32; off; off >>= 1) sum += __shfl_xor(sum, off);
    #pragma unroll
    for (int i = 0; i < 16; ++i) {
      size_t idx = (size_t)(g0 + r1) * Z_DIM + 64 * i + lane;
      float p = s[i] / sum;
      P[idx] = p;
      if (Pb) Pb[idx] = f32_to_bf16(p);
    }
  }
}

// ---------------------------------------------------------------------------
// Kernel G (R12): 256x256xBK=32 8-phase GEMM, 64 KB LDS -> 2 blocks/CU.
// Same verified phase skeleton as R11 (incl. peeled last iter); changes are
// parameterization only:
//   - A/B tiles 256x32 (16 KB; halves 8 KB); STAGE = 1 gload/thread.
//   - vmcnt(3) at p4/p8 (3 half-tiles in flight x 1 load). Peel: vmcnt(0).
//   - LDS: 128 super-rows (2 rows of 32 elems) x 8 units(16B); physical unit
//     p at super-row sr holds logical q = p ^ (sr&7) (involution; read ~2-way
//     conflict-free like the verified BK=64 layout).
//   - 32 K-tiles: 16 iterations (i<15 main + peel); t3max=31, no wrap.
// ---------------------------------------------------------------------------
#define ABUF0 0
#define BBUF0 16384
#define ABUF1 32768
#define BBUF1 49152
#define HALF_T 8192

__global__ __launch_bounds__(512, 4) void recon_mfma8_kernel(
    const ushort* __restrict__ Pb, const ushort* __restrict__ Vt,
    float* __restrict__ C) {
  __shared__ __attribute__((aligned(16))) char smem[65536];

  const int t    = threadIdx.x;
  const int m0   = blockIdx.y * 256;
  const int n0   = blockIdx.x * 256;
  const int wave = t >> 6, lane = t & 63;
  const int wr64 = (wave >> 2) * 64;
  const int wc32 = (wave & 3) * 32;
  const int fr   = lane & 15, lhi = lane >> 4;
  // staging: thread t -> super-row sr=t>>3, physical unit p=t&7,
  // logical unit q = p ^ (sr&7): global row = 2*sr + (q>>2), k-unit = q&3.
  const int s_sr = t >> 3;
  const int s_q  = (t & 7) ^ (s_sr & 7);
  const int s_row = 2 * s_sr + (s_q >> 2);
  const int s_ku  = s_q & 3;

#define STAGE(srcP, rowb, ldsbase, tile) do {                                 \
    gload_lds16(srcP + (size_t)((rowb) + s_row) * Z_DIM +                     \
                    (size_t)(tile) * 32 + s_ku * 8,                           \
                smem + (ldsbase) + t * 16);                                   \
  } while (0)

#define LOAD_A(qm, abase) do {                                                \
    _Pragma("unroll") for (int mi_ = 0; mi_ < 4; ++mi_) {                     \
      int row_ = (qm) * 128 + wr64 + mi_ * 16 + fr;                           \
      int sr_  = row_ >> 1;                                                   \
      int p_   = (((row_ & 1) << 2) | lhi) ^ (sr_ & 7);                       \
      a[mi_] = *(const bf16x8*)(smem + (abase) + sr_ * 128 + p_ * 16);        \
    } } while (0)

#define LOAD_B(dst, qn, bbase) do {                                           \
    _Pragma("unroll") for (int ni_ = 0; ni_ < 2; ++ni_) {                     \
      int row_ = (qn) * 128 + wc32 + ni_ * 16 + fr;                           \
      int sr_  = row_ >> 1;                                                   \
      int p_   = (((row_ & 1) << 2) | lhi) ^ (sr_ & 7);                       \
      dst[ni_] = *(const bf16x8*)(smem + (bbase) + sr_ * 128 + p_ * 16);      \
    } } while (0)

#define MFMAQ(qm, qn, bb) do {                                                \
    __builtin_amdgcn_s_setprio(1);                                            \
    _Pragma("unroll") for (int mi_ = 0; mi_ < 4; ++mi_)                       \
    _Pragma("unroll") for (int ni_ = 0; ni_ < 2; ++ni_)                       \
      acc[qm][mi_][qn][ni_] = __builtin_amdgcn_mfma_f32_16x16x32_bf16(        \
          a[mi_], bb[ni_], acc[qm][mi_][qn][ni_], 0, 0, 0);                   \
    __builtin_amdgcn_s_setprio(0);                                            \
  } while (0)

#define BARF()  do { __builtin_amdgcn_s_barrier();                            \
                     __builtin_amdgcn_sched_barrier(0); } while (0)
#define LGKM0() do { asm volatile("s_waitcnt lgkmcnt(0)" ::: "memory");       \
                     __builtin_amdgcn_sched_barrier(0); } while (0)
#define VM3()   do { asm volatile("s_waitcnt vmcnt(3)" ::: "memory");         \
                     __builtin_amdgcn_sched_barrier(0); } while (0)
#define VM0()   do { asm volatile("s_waitcnt vmcnt(0)" ::: "memory");         \
                     __builtin_amdgcn_sched_barrier(0); } while (0)

  f32x4 acc[2][4][2][2] = {};
  bf16x8 a[4], b0[2], b1[2];

  // ---- prologue: tile0 -> buf0 (4 halves); tile1 -> buf1 (A0,B0,B1) ----
  STAGE(Pb, m0,       ABUF0,          0);
  STAGE(Pb, m0 + 128, ABUF0 + HALF_T, 0);
  STAGE(Vt, n0,       BBUF0,          0);
  STAGE(Vt, n0 + 128, BBUF0 + HALF_T, 0);
  STAGE(Pb, m0,       ABUF1,          1);
  STAGE(Vt, n0,       BBUF1,          1);
  STAGE(Vt, n0 + 128, BBUF1 + HALF_T, 1);
  VM3();     // 7 issued; drain tile0's 4, leave tile1's 3 in flight
  BARF();

  // ---- main loop: iterations 0..14 (tiles 0..29 computed, ..31 staged) ----
  for (int i = 0; i < 15; ++i) {
    const int t1 = 2 * i + 1;
    const int t2 = 2 * i + 2;
    const int t3 = 2 * i + 3;

    LOAD_A(0, ABUF0); LOAD_B(b0, 0, BBUF0);
    STAGE(Pb, m0 + 128, ABUF1 + HALF_T, t1);
    BARF(); LGKM0();
    MFMAQ(0, 0, b0);
    BARF();

    LOAD_B(b1, 1, BBUF0);
    STAGE(Pb, m0, ABUF0, t2);
    BARF(); LGKM0();
    MFMAQ(0, 1, b1);
    BARF();

    LOAD_A(1, ABUF0);
    STAGE(Vt, n0, BBUF0, t2);
    BARF(); LGKM0();
    MFMAQ(1, 1, b1);
    BARF();

    STAGE(Vt, n0 + 128, BBUF0 + HALF_T, t2);
    VM3();   // drain t1's 4 stages -> buf1 complete; t2's A0,B0,B1 in flight
    BARF();
    MFMAQ(1, 0, b0);
    BARF();

    LOAD_A(0, ABUF1); LOAD_B(b0, 0, BBUF1);
    STAGE(Pb, m0 + 128, ABUF0 + HALF_T, t2);
    BARF(); LGKM0();
    MFMAQ(0, 0, b0);
    BARF();

    LOAD_B(b1, 1, BBUF1);
    STAGE(Pb, m0, ABUF1, t3);
    BARF(); LGKM0();
    MFMAQ(0, 1, b1);
    BARF();

    LOAD_A(1, ABUF1);
    STAGE(Vt, n0, BBUF1, t3);
    BARF(); LGKM0();
    MFMAQ(1, 1, b1);
    BARF();

    STAGE(Vt, n0 + 128, BBUF1 + HALF_T, t3);
    VM3();   // drain t2's A0,B0,B1,A1 -> buf0 complete; t3's 3 in flight
    BARF();
    MFMAQ(1, 0, b0);
    BARF();
  }

  // ---- peeled i=15 (tiles 30,31): no junk prefetch ----
  LOAD_A(0, ABUF0); LOAD_B(b0, 0, BBUF0);
  STAGE(Pb, m0 + 128, ABUF1 + HALF_T, 31);
  BARF(); LGKM0();
  MFMAQ(0, 0, b0);
  BARF();

  LOAD_B(b1, 1, BBUF0);
  BARF(); LGKM0();
  MFMAQ(0, 1, b1);
  BARF();

  LOAD_A(1, ABUF0);
  BARF(); LGKM0();
  MFMAQ(1, 1, b1);
  BARF();

  VM0();   // drain: buf1 tile31 (A0,B0,B1 from i=14; A1 from p1) ready
  BARF();
  MFMAQ(1, 0, b0);
  BARF();

  LOAD_A(0, ABUF1); LOAD_B(b0, 0, BBUF1);
  BARF(); LGKM0();
  MFMAQ(0, 0, b0);
  BARF();

  LOAD_B(b1, 1, BBUF1);
  BARF(); LGKM0();
  MFMAQ(0, 1, b1);
  BARF();

  LOAD_A(1, ABUF1);
  BARF(); LGKM0();
  MFMAQ(1, 1, b1);

  MFMAQ(1, 0, b0);   // register-only; no further waits needed

  // ---- epilogue: C[row][col], frag D: col=lane&15, row=(lane>>4)*4+reg ----
  #pragma unroll
  for (int qm = 0; qm < 2; ++qm)
  #pragma unroll
  for (int mi = 0; mi < 4; ++mi)
  #pragma unroll
  for (int qn = 0; qn < 2; ++qn)
  #pragma unroll
  for (int ni = 0; ni < 2; ++ni) {
    f32x4 v = acc[qm][mi][qn][ni];
    int row0 = m0 + qm * 128 + wr64 + mi * 16 + lhi * 4;
    int col  = n0 + qn * 128 + wc32 + ni * 16 + fr;
    #pragma unroll
    for (int r = 0; r < 4; ++r)
      C[(size_t)(row0 + r) * N_CELLS + col] = v[r];
  }
}

// ---------------------------------------------------------------------------
// Fallback f32 GEMM (used only if ws is far too small)
// ---------------------------------------------------------------------------
#define BM 128
#define BN 128
#define BK 16

__global__ __launch_bounds__(256) void recon_gemm_kernel(
    const float* __restrict__ P, const float* __restrict__ V,
    float* __restrict__ C) {
  __shared__ float As[BK][BM + 4];
  __shared__ float Bs[BK][BN + 4];

  const int t  = threadIdx.x;
  const int m0 = blockIdx.y * BM;
  const int n0 = blockIdx.x * BN;
  const int tx = t % 16, ty = t / 16;

  float acc[8][8] = {};

  for (int k0 = 0; k0 < Z_DIM; k0 += BK) {
    {
      int r = t / 4, q = t % 4;
      #pragma unroll
      for (int h = 0; h < 2; ++h) {
        int row = r + 64 * h;
        float4 v = *(const float4*)&P[(size_t)(m0 + row) * Z_DIM + k0 + q * 4];
        As[q * 4 + 0][row] = v.x;
        As[q * 4 + 1][row] = v.y;
        As[q * 4 + 2][row] = v.z;
        As[q * 4 + 3][row] = v.w;
      }
    }
    {
      int kr = t / 32, c4 = t % 32;
      #pragma unroll
      for (int h = 0; h < 2; ++h) {
        int row = kr + 8 * h;
        float4 v = *(const float4*)&V[(size_t)(k0 + row) * N_CELLS + n0 + c4 * 4];
        *(float4*)&Bs[row][c4 * 4] = v;
      }
    }
    __syncthreads();
    #pragma unroll
    for (int kk = 0; kk < BK; ++kk) {
      float aa[8], bb[8];
      *(float4*)&aa[0] = *(const float4*)&As[kk][ty * 8];
      *(float4*)&aa[4] = *(const float4*)&As[kk][ty * 8 + 4];
      *(float4*)&bb[0] = *(const float4*)&Bs[kk][tx * 8];
      *(float4*)&bb[4] = *(const float4*)&Bs[kk][tx * 8 + 4];
      #pragma unroll
      for (int i = 0; i < 8; ++i)
        #pragma unroll
        for (int j = 0; j < 8; ++j)
          acc[i][j] = fmaf(aa[i], bb[j], acc[i][j]);
    }
    __syncthreads();
  }

  #pragma unroll
  for (int i = 0; i < 8; ++i) {
    int row = m0 + ty * 8 + i;
    #pragma unroll
    for (int j4 = 0; j4 < 2; ++j4) {
      float4 v = make_float4(acc[i][j4 * 4 + 0], acc[i][j4 * 4 + 1],
                             acc[i][j4 * 4 + 2], acc[i][j4 * 4 + 3]);
      *(float4*)&C[(size_t)row * N_CELLS + n0 + tx * 8 + j4 * 4] = v;
    }
  }
}

extern "C" void kernel_launch(void* const* d_in, const int* in_sizes, int n_in,
                              void* d_out, int out_size, void* d_ws, size_t ws_size,
                              hipStream_t stream) {
  const float* Q = (const float*)d_in[0];  // 16384 x 128
  const float* K = (const float*)d_in[1];  // 1024 x 128
  const float* V = (const float*)d_in[2];  // 1024 x 4096
  float* recon = (float*)d_out;                          // 16384 x 4096
  float* P     = recon + (size_t)N_GENES * N_CELLS;      // 16384 x 1024

  const size_t pb_elems = (size_t)N_GENES * Z_DIM;   // 16.8M
  const size_t vt_elems = (size_t)Z_DIM * N_CELLS;   // 4.2M
  const size_t q_elems  = (size_t)N_GENES * D_K;     // 2.1M
  const size_t k_elems  = (size_t)Z_DIM * D_K;       // 131K

  const size_t need_mid  = (pb_elems + vt_elems) * sizeof(ushort);
  const size_t need_full = need_mid + 2 * (q_elems + k_elems) * sizeof(ushort);

  if (ws_size >= need_full) {
    ushort* Pb  = (ushort*)d_ws;
    ushort* Vtb = Pb + pb_elems;
    ushort* Qh  = Vtb + vt_elems;
    ushort* Ql  = Qh + q_elems;
    ushort* Kh  = Ql + q_elems;
    ushort* Kl  = Kh + k_elems;
    prep_kernel<<<dim3(NB_HILO + 1024), 256, 0, stream>>>(
        Q, K, V, Qh, Ql, Kh, Kl, Vtb);
    attn_mfma_kernel<<<dim3(N_GENES / 16), 256, 0, stream>>>(
        Qh, Ql, Kh, Kl, P, Pb);
    recon_mfma8_kernel<<<dim3(N_CELLS / 256, N_GENES / 256), 512, 0, stream>>>(
        Pb, Vtb, recon);
  } else if (ws_size >= need_mid) {
    ushort* Pb  = (ushort*)d_ws;
    ushort* Vtb = Pb + pb_elems;
    attn_p_kernel<<<dim3(N_GENES / 8), 256, 0, stream>>>(Q, K, P, Pb);
    recon_mfma8_kernel<<<dim3(N_CELLS / 256, N_GENES / 256), 512, 0, stream>>>(
        Pb, Vtb, recon);
  } else {
    attn_p_kernel<<<dim3(N_GENES / 8), 256, 0, stream>>>(Q, K, P, nullptr);
    recon_gemm_kernel<<<dim3(N_CELLS / BN, N_GENES / BM), 256, 0, stream>>>(
        P, V, recon);
  }
}

// Round 13
// 233.426 us; speedup vs baseline: 6.2810x; 6.2810x over previous
//
#include <hip/hip_runtime.h>
#include <stdint.h>

#define N_GENES 16384
#define Z_DIM   1024
#define D_K     128
#define N_CELLS 4096

typedef __attribute__((ext_vector_type(8))) short bf16x8;
typedef __attribute__((ext_vector_type(4))) float f32x4;

// ---------------------------------------------------------------------------
// JAX threefry2x32 (20 rounds) — verified variant: partitionable, bits1^bits2
// ---------------------------------------------------------------------------
__device__ __forceinline__ uint32_t rotl32(uint32_t x, int r) {
  return (x << r) | (x >> (32 - r));
}

__device__ __forceinline__ void threefry2x32(uint32_t k0, uint32_t k1,
                                             uint32_t& x0, uint32_t& x1) {
  const uint32_t ks2 = k0 ^ k1 ^ 0x1BD11BDAu;
  x0 += k0; x1 += k1;
#define TF_ROUND(r) { x0 += x1; x1 = rotl32(x1, (r)); x1 ^= x0; }
  TF_ROUND(13) TF_ROUND(15) TF_ROUND(26) TF_ROUND(6)
  x0 += k1;  x1 += ks2 + 1u;
  TF_ROUND(17) TF_ROUND(29) TF_ROUND(16) TF_ROUND(24)
  x0 += ks2; x1 += k0 + 2u;
  TF_ROUND(13) TF_ROUND(15) TF_ROUND(26) TF_ROUND(6)
  x0 += k0;  x1 += k1 + 3u;
  TF_ROUND(17) TF_ROUND(29) TF_ROUND(16) TF_ROUND(24)
  x0 += k1;  x1 += ks2 + 4u;
  TF_ROUND(13) TF_ROUND(15) TF_ROUND(26) TF_ROUND(6)
  x0 += ks2; x1 += k0 + 5u;
#undef TF_ROUND
}

__device__ __forceinline__ float gumbel_from(uint32_t n) {
  uint32_t x0 = 0u, x1 = n;   // counter = (hi, lo) of uint64 flat index
  threefry2x32(0u, 42u, x0, x1);
  uint32_t bits = x0 ^ x1;    // partitionable sub-64-bit fold  (R3-verified)
  float f = __uint_as_float((bits >> 9) | 0x3F800000u) - 1.0f;
  const float tiny = 1.17549435082228751e-38f;
  float u = fmaxf(tiny, f + tiny);
  return -logf(-logf(u));
}

__device__ __forceinline__ ushort f32_to_bf16(float x) {
  uint32_t u = __float_as_uint(x);
  uint32_t r = (u + 0x7FFFu + ((u >> 16) & 1u)) >> 16;  // RNE
  return (ushort)r;
}

__device__ __forceinline__ float bf16_to_f32(ushort h) {
  return __uint_as_float(((uint32_t)h) << 16);
}

__device__ __forceinline__ void gload_lds16(const void* g, void* l) {
  __builtin_amdgcn_global_load_lds(
      (const __attribute__((address_space(1))) unsigned int*)g,
      (__attribute__((address_space(3))) unsigned int*)l, 16, 0, 0);
}

// ---------------------------------------------------------------------------
// Kernel P: fused prep (R8-retained). Blocks [0, NB_HILO) do hi/lo split of
// Q then K; blocks [NB_HILO, +1024) transpose+convert V -> Vt bf16.
// ---------------------------------------------------------------------------
#define HILO_Q_N4 (N_GENES * D_K / 4)            // 524288
#define HILO_K_N4 (Z_DIM * D_K / 4)              // 32768
#define NB_HILO   ((HILO_Q_N4 + HILO_K_N4) / 256)  // 2176

__global__ __launch_bounds__(256) void prep_kernel(
    const float* __restrict__ Q, const float* __restrict__ K,
    const float* __restrict__ V,
    ushort* __restrict__ Qh, ushort* __restrict__ Ql,
    ushort* __restrict__ Kh, ushort* __restrict__ Kl,
    ushort* __restrict__ Vt) {
  const int b = blockIdx.x;
  const int t = threadIdx.x;

  if (b < NB_HILO) {
    int i = b * 256 + t;
    const float* src; ushort* hi; ushort* lo;
    if (i < HILO_Q_N4) { src = Q; hi = Qh; lo = Ql; }
    else { i -= HILO_Q_N4; src = K; hi = Kh; lo = Kl; }
    float4 v = ((const float4*)src)[i];
    ushort4 h, l;
    h.x = f32_to_bf16(v.x); l.x = f32_to_bf16(v.x - bf16_to_f32(h.x));
    h.y = f32_to_bf16(v.y); l.y = f32_to_bf16(v.y - bf16_to_f32(h.y));
    h.z = f32_to_bf16(v.z); l.z = f32_to_bf16(v.z - bf16_to_f32(h.z));
    h.w = f32_to_bf16(v.w); l.w = f32_to_bf16(v.w - bf16_to_f32(h.w));
    ((ushort4*)hi)[i] = h;
    ((ushort4*)lo)[i] = l;
    return;
  }

  // V transpose: vb in [0, 1024) -> 64x64 tile
  __shared__ ushort tile[64][68];
  const int vb = b - NB_HILO;
  const int n0 = (vb & 63) * 64;   // cell block
  const int k0 = (vb >> 6) * 64;   // z block

  #pragma unroll
  for (int j = 0; j < 4; ++j) {
    int e = j * 1024 + t * 4;
    int r = e >> 6, c = e & 63;
    float4 v = *(const float4*)&V[(size_t)(k0 + r) * N_CELLS + n0 + c];
    tile[r][c + 0] = f32_to_bf16(v.x);
    tile[r][c + 1] = f32_to_bf16(v.y);
    tile[r][c + 2] = f32_to_bf16(v.z);
    tile[r][c + 3] = f32_to_bf16(v.w);
  }
  __syncthreads();
  #pragma unroll
  for (int j = 0; j < 4; ++j) {
    int u = j * 256 + t;
    int n = u >> 4, kb = (u & 15) * 4;
    ushort4 o;
    o.x = tile[kb + 0][n]; o.y = tile[kb + 1][n];
    o.z = tile[kb + 2][n]; o.w = tile[kb + 3][n];
    *(ushort4*)&Vt[(size_t)(n0 + n) * Z_DIM + k0 + kb] = o;
  }
}

// ---------------------------------------------------------------------------
// Kernel A (MFMA): scores via split-bf16 3-pass MFMA + gumbel-softmax.
// (R7-verified) 16 genes/block, 4 waves; K chunks double-buffered, swizzled.
// ---------------------------------------------------------------------------
__global__ __launch_bounds__(256) void attn_mfma_kernel(
    const ushort* __restrict__ Qh, const ushort* __restrict__ Ql,
    const ushort* __restrict__ Kh, const ushort* __restrict__ Kl,
    float* __restrict__ P, ushort* __restrict__ Pb) {
  __shared__ __attribute__((aligned(16))) ushort qsm[2][16][128];      // [h/l]
  __shared__ __attribute__((aligned(16))) ushort ksm[2][2][64][128];   // [buf][h/l]
  __shared__ float redmax[4][16];
  __shared__ float redsum[4][16];

  const int t    = threadIdx.x;
  const int g0   = blockIdx.x * 16;
  const int wave = t >> 6, lane = t & 63;
  const int fr   = lane & 15, lhi = lane >> 4;

  {
    int un = t, row = un >> 4, usrc = (un & 15) ^ (row & 7);
    gload_lds16(Qh + (size_t)(g0 + row) * D_K + usrc * 8, &qsm[0][0][0] + un * 8);
    gload_lds16(Ql + (size_t)(g0 + row) * D_K + usrc * 8, &qsm[1][0][0] + un * 8);
  }

#define KSTAGE(buf, zc) do {                                                  \
    _Pragma("unroll") for (int j_ = 0; j_ < 4; ++j_) {                        \
      int un_ = j_ * 256 + t, row_ = un_ >> 4;                                \
      int us_ = (un_ & 15) ^ (row_ & 7);                                      \
      gload_lds16(Kh + (size_t)((zc) + row_) * D_K + us_ * 8,                 \
                  &ksm[buf][0][0][0] + un_ * 8);                              \
      gload_lds16(Kl + (size_t)((zc) + row_) * D_K + us_ * 8,                 \
                  &ksm[buf][1][0][0] + un_ * 8);                              \
    } } while (0)

  KSTAGE(0, 0);
  __syncthreads();

  bf16x8 ah[4], al[4];
  #pragma unroll
  for (int ks = 0; ks < 4; ++ks) {
    int q = (ks * 4 + lhi) ^ (fr & 7);
    ah[ks] = *(const bf16x8*)(&qsm[0][fr][0] + q * 8);
    al[ks] = *(const bf16x8*)(&qsm[1][fr][0] + q * 8);
  }

  f32x4 acc[16] = {};
  const int rowk = wave * 16 + fr;

  #pragma unroll
  for (int c = 0; c < 16; ++c) {
    if (c < 15) KSTAGE((c + 1) & 1, (c + 1) * 64);
    const ushort* kbh = &ksm[c & 1][0][0][0];
    const ushort* kbl = &ksm[c & 1][1][0][0];
    #pragma unroll
    for (int ks = 0; ks < 4; ++ks) {
      int q = (ks * 4 + lhi) ^ (fr & 7);
      bf16x8 bh = *(const bf16x8*)(kbh + rowk * 128 + q * 8);
      bf16x8 bl = *(const bf16x8*)(kbl + rowk * 128 + q * 8);
      acc[c] = __builtin_amdgcn_mfma_f32_16x16x32_bf16(ah[ks], bh, acc[c], 0, 0, 0);
      acc[c] = __builtin_amdgcn_mfma_f32_16x16x32_bf16(ah[ks], bl, acc[c], 0, 0, 0);
      acc[c] = __builtin_amdgcn_mfma_f32_16x16x32_bf16(al[ks], bh, acc[c], 0, 0, 0);
    }
    __syncthreads();
  }
#undef KSTAGE

  const float scale = 0.08838834764831845f;  // 1/sqrt(128)

  #pragma unroll
  for (int c = 0; c < 16; ++c) {
    #pragma unroll
    for (int r = 0; r < 4; ++r) {
      uint32_t gene = (uint32_t)(g0 + lhi * 4 + r);
      uint32_t z    = (uint32_t)(c * 64 + wave * 16 + fr);
      acc[c][r] = fmaf(acc[c][r], scale, gumbel_from(gene * (uint32_t)Z_DIM + z));
    }
  }

  float m[4] = {-INFINITY, -INFINITY, -INFINITY, -INFINITY};
  #pragma unroll
  for (int c = 0; c < 16; ++c)
    #pragma unroll
    for (int r = 0; r < 4; ++r) m[r] = fmaxf(m[r], acc[c][r]);
  #pragma unroll
  for (int off = 1; off <= 8; off <<= 1)
    #pragma unroll
    for (int r = 0; r < 4; ++r) m[r] = fmaxf(m[r], __shfl_xor(m[r], off));
  if (fr == 0) {
    #pragma unroll
    for (int r = 0; r < 4; ++r) redmax[wave][lhi * 4 + r] = m[r];
  }
  __syncthreads();
  #pragma unroll
  for (int r = 0; r < 4; ++r) {
    int g = lhi * 4 + r;
    m[r] = fmaxf(fmaxf(redmax[0][g], redmax[1][g]),
                 fmaxf(redmax[2][g], redmax[3][g]));
  }

  float sum[4] = {0.f, 0.f, 0.f, 0.f};
  #pragma unroll
  for (int c = 0; c < 16; ++c)
    #pragma unroll
    for (int r = 0; r < 4; ++r) {
      acc[c][r] = expf(acc[c][r] - m[r]);
      sum[r] += acc[c][r];
    }
  #pragma unroll
  for (int off = 1; off <= 8; off <<= 1)
    #pragma unroll
    for (int r = 0; r < 4; ++r) sum[r] += __shfl_xor(sum[r], off);
  if (fr == 0) {
    #pragma unroll
    for (int r = 0; r < 4; ++r) redsum[wave][lhi * 4 + r] = sum[r];
  }
  __syncthreads();
  float inv[4];
  #pragma unroll
  for (int r = 0; r < 4; ++r) {
    int g = lhi * 4 + r;
    inv[r] = 1.0f / (redsum[0][g] + redsum[1][g] + redsum[2][g] + redsum[3][g]);
  }

  #pragma unroll
  for (int c = 0; c < 16; ++c)
    #pragma unroll
    for (int r = 0; r < 4; ++r) {
      float p = acc[c][r] * inv[r];
      size_t idx = (size_t)(g0 + lhi * 4 + r) * Z_DIM + c * 64 + wave * 16 + fr;
      P[idx] = p;
      Pb[idx] = f32_to_bf16(p);
    }
}

// ---------------------------------------------------------------------------
// Kernel A-fallback (f32 VALU, R3-verified) — used only if ws too small.
// ---------------------------------------------------------------------------
__global__ __launch_bounds__(256) void attn_p_kernel(
    const float* __restrict__ Q, const float* __restrict__ K,
    float* __restrict__ P, ushort* __restrict__ Pb) {
  __shared__ float  qs[8][128];
  __shared__ float4 kk4[64][32];

  const int t    = threadIdx.x;
  const int g0   = blockIdx.x * 8;
  const int wave = t >> 6, lane = t & 63;

  {
    int r = t / 32, c4 = t % 32;
    *(float4*)&qs[r][c4 * 4] =
        *(const float4*)&Q[(size_t)(g0 + r) * D_K + c4 * 4];
  }

  const int r0 = wave * 2, r1 = wave * 2 + 1;
  float sA[16], sB[16];

  for (int c = 0; c < 16; ++c) {
    const int zc = c * 64;
    __syncthreads();
    #pragma unroll
    for (int i = 0; i < 8; ++i) {
      int fidx = t + 256 * i;
      int zr = fidx / 32, c4 = fidx % 32;
      float4 v = *(const float4*)&K[(size_t)(zc + zr) * D_K + c4 * 4];
      kk4[zr][c4 ^ (zr & 31)] = v;
    }
    __syncthreads();
    float s0 = 0.f, s1 = 0.f;
    #pragma unroll
    for (int d4 = 0; d4 < 32; ++d4) {
      float4 kv = kk4[lane][d4 ^ (lane & 31)];
      float4 q0 = *(const float4*)&qs[r0][d4 * 4];
      float4 q1 = *(const float4*)&qs[r1][d4 * 4];
      s0 = fmaf(q0.x, kv.x, s0); s0 = fmaf(q0.y, kv.y, s0);
      s0 = fmaf(q0.z, kv.z, s0); s0 = fmaf(q0.w, kv.w, s0);
      s1 = fmaf(q1.x, kv.x, s1); s1 = fmaf(q1.y, kv.y, s1);
      s1 = fmaf(q1.z, kv.z, s1); s1 = fmaf(q1.w, kv.w, s1);
    }
    sA[c] = s0; sB[c] = s1;
  }

  const float scale = 0.08838834764831845f;

  {
    float s[16]; float mx = -INFINITY;
    #pragma unroll
    for (int i = 0; i < 16; ++i) {
      uint32_t n = (uint32_t)((g0 + r0) * Z_DIM + 64 * i + lane);
      s[i] = fmaf(sA[i], scale, gumbel_from(n));
      mx = fmaxf(mx, s[i]);
    }
    #pragma unroll
    for (int off = 32; off; off >>= 1) mx = fmaxf(mx, __shfl_xor(mx, off));
    float sum = 0.f;
    #pragma unroll
    for (int i = 0; i < 16; ++i) { s[i] = expf(s[i] - mx); sum += s[i]; }
    #pragma unroll
    for (int off = 32; off; off >>= 1) sum += __shfl_xor(sum, off);
    #pragma unroll
    for (int i = 0; i < 16; ++i) {
      size_t idx = (size_t)(g0 + r0) * Z_DIM + 64 * i + lane;
      float p = s[i] / sum;
      P[idx] = p;
      if (Pb) Pb[idx] = f32_to_bf16(p);
    }
  }
  {
    float s[16]; float mx = -INFINITY;
    #pragma unroll
    for (int i = 0; i < 16; ++i) {
      uint32_t n = (uint32_t)((g0 + r1) * Z_DIM + 64 * i + lane);
      s[i] = fmaf(sB[i], scale, gumbel_from(n));
      mx = fmaxf(mx, s[i]);
    }
    #pragma unroll
    for (int off = 32; off; off >>= 1) mx = fmaxf(mx, __shfl_xor(mx, off));
    float sum = 0.f;
    #pragma unroll
    for (int i = 0; i < 16; ++i) { s[i] = expf(s[i] - mx); sum += s[i]; }
    #pragma unroll
    for (int off = 32; off; off >>= 1) sum += __shfl_xor(sum, off);
    #pragma unroll
    for (int i = 0; i < 16; ++i) {
      size_t idx = (size_t)(g0 + r1) * Z_DIM + 64 * i + lane;
      float p = s[i] / sum;
      P[idx] = p;
      if (Pb) Pb[idx] = f32_to_bf16(p);
    }
  }
}

// ---------------------------------------------------------------------------
// Kernel G (R13): 256x256xBK=32 8-phase GEMM, 64 KB LDS.
// Identical to R12 (schedule verified correct: absmax passed) EXCEPT
// __launch_bounds__(512, 2): R12's (512,4) forced VGPR=64 -> acc spilled to
// scratch (WRITE_SIZE 4.3 GB). With (512,2) the allocator floats (~110-128
// VGPR, no spill); <=128 VGPR + 64 KB LDS => 2 blocks/CU by hardware limits.
// ---------------------------------------------------------------------------
#define ABUF0 0
#define BBUF0 16384
#define ABUF1 32768
#define BBUF1 49152
#define HALF_T 8192

__global__ __launch_bounds__(512, 2) void recon_mfma8_kernel(
    const ushort* __restrict__ Pb, const ushort* __restrict__ Vt,
    float* __restrict__ C) {
  __shared__ __attribute__((aligned(16))) char smem[65536];

  const int t    = threadIdx.x;
  const int m0   = blockIdx.y * 256;
  const int n0   = blockIdx.x * 256;
  const int wave = t >> 6, lane = t & 63;
  const int wr64 = (wave >> 2) * 64;
  const int wc32 = (wave & 3) * 32;
  const int fr   = lane & 15, lhi = lane >> 4;
  // staging: thread t -> super-row sr=t>>3, physical unit p=t&7,
  // logical unit q = p ^ (sr&7): global row = 2*sr + (q>>2), k-unit = q&3.
  const int s_sr = t >> 3;
  const int s_q  = (t & 7) ^ (s_sr & 7);
  const int s_row = 2 * s_sr + (s_q >> 2);
  const int s_ku  = s_q & 3;

#define STAGE(srcP, rowb, ldsbase, tile) do {                                 \
    gload_lds16(srcP + (size_t)((rowb) + s_row) * Z_DIM +                     \
                    (size_t)(tile) * 32 + s_ku * 8,                           \
                smem + (ldsbase) + t * 16);                                   \
  } while (0)

#define LOAD_A(qm, abase) do {                                                \
    _Pragma("unroll") for (int mi_ = 0; mi_ < 4; ++mi_) {                     \
      int row_ = (qm) * 128 + wr64 + mi_ * 16 + fr;                           \
      int sr_  = row_ >> 1;                                                   \
      int p_   = (((row_ & 1) << 2) | lhi) ^ (sr_ & 7);                       \
      a[mi_] = *(const bf16x8*)(smem + (abase) + sr_ * 128 + p_ * 16);        \
    } } while (0)

#define LOAD_B(dst, qn, bbase) do {                                           \
    _Pragma("unroll") for (int ni_ = 0; ni_ < 2; ++ni_) {                     \
      int row_ = (qn) * 128 + wc32 + ni_ * 16 + fr;                           \
      int sr_  = row_ >> 1;                                                   \
      int p_   = (((row_ & 1) << 2) | lhi) ^ (sr_ & 7);                       \
      dst[ni_] = *(const bf16x8*)(smem + (bbase) + sr_ * 128 + p_ * 16);      \
    } } while (0)

#define MFMAQ(qm, qn, bb) do {                                                \
    __builtin_amdgcn_s_setprio(1);                                            \
    _Pragma("unroll") for (int mi_ = 0; mi_ < 4; ++mi_)                       \
    _Pragma("unroll") for (int ni_ = 0; ni_ < 2; ++ni_)                       \
      acc[qm][mi_][qn][ni_] = __builtin_amdgcn_mfma_f32_16x16x32_bf16(        \
          a[mi_], bb[ni_], acc[qm][mi_][qn][ni_], 0, 0, 0);                   \
    __builtin_amdgcn_s_setprio(0);                                            \
  } while (0)

#define BARF()  do { __builtin_amdgcn_s_barrier();                            \
                     __builtin_amdgcn_sched_barrier(0); } while (0)
#define LGKM0() do { asm volatile("s_waitcnt lgkmcnt(0)" ::: "memory");       \
                     __builtin_amdgcn_sched_barrier(0); } while (0)
#define VM3()   do { asm volatile("s_waitcnt vmcnt(3)" ::: "memory");         \
                     __builtin_amdgcn_sched_barrier(0); } while (0)
#define VM0()   do { asm volatile("s_waitcnt vmcnt(0)" ::: "memory");         \
                     __builtin_amdgcn_sched_barrier(0); } while (0)

  f32x4 acc[2][4][2][2] = {};
  bf16x8 a[4], b0[2], b1[2];

  // ---- prologue: tile0 -> buf0 (4 halves); tile1 -> buf1 (A0,B0,B1) ----
  STAGE(Pb, m0,       ABUF0,          0);
  STAGE(Pb, m0 + 128, ABUF0 + HALF_T, 0);
  STAGE(Vt, n0,       BBUF0,          0);
  STAGE(Vt, n0 + 128, BBUF0 + HALF_T, 0);
  STAGE(Pb, m0,       ABUF1,          1);
  STAGE(Vt, n0,       BBUF1,          1);
  STAGE(Vt, n0 + 128, BBUF1 + HALF_T, 1);
  VM3();     // 7 issued; drain tile0's 4, leave tile1's 3 in flight
  BARF();

  // ---- main loop: iterations 0..14 (tiles 0..29 computed, ..31 staged) ----
  for (int i = 0; i < 15; ++i) {
    const int t1 = 2 * i + 1;
    const int t2 = 2 * i + 2;
    const int t3 = 2 * i + 3;

    LOAD_A(0, ABUF0); LOAD_B(b0, 0, BBUF0);
    STAGE(Pb, m0 + 128, ABUF1 + HALF_T, t1);
    BARF(); LGKM0();
    MFMAQ(0, 0, b0);
    BARF();

    LOAD_B(b1, 1, BBUF0);
    STAGE(Pb, m0, ABUF0, t2);
    BARF(); LGKM0();
    MFMAQ(0, 1, b1);
    BARF();

    LOAD_A(1, ABUF0);
    STAGE(Vt, n0, BBUF0, t2);
    BARF(); LGKM0();
    MFMAQ(1, 1, b1);
    BARF();

    STAGE(Vt, n0 + 128, BBUF0 + HALF_T, t2);
    VM3();   // drain t1's 4 stages -> buf1 complete; t2's A0,B0,B1 in flight
    BARF();
    MFMAQ(1, 0, b0);
    BARF();

    LOAD_A(0, ABUF1); LOAD_B(b0, 0, BBUF1);
    STAGE(Pb, m0 + 128, ABUF0 + HALF_T, t2);
    BARF(); LGKM0();
    MFMAQ(0, 0, b0);
    BARF();

    LOAD_B(b1, 1, BBUF1);
    STAGE(Pb, m0, ABUF1, t3);
    BARF(); LGKM0();
    MFMAQ(0, 1, b1);
    BARF();

    LOAD_A(1, ABUF1);
    STAGE(Vt, n0, BBUF1, t3);
    BARF(); LGKM0();
    MFMAQ(1, 1, b1);
    BARF();

    STAGE(Vt, n0 + 128, BBUF1 + HALF_T, t3);
    VM3();   // drain t2's A0,B0,B1,A1 -> buf0 complete; t3's 3 in flight
    BARF();
    MFMAQ(1, 0, b0);
    BARF();
  }

  // ---- peeled i=15 (tiles 30,31): no junk prefetch ----
  LOAD_A(0, ABUF0); LOAD_B(b0, 0, BBUF0);
  STAGE(Pb, m0 + 128, ABUF1 + HALF_T, 31);
  BARF(); LGKM0();
  MFMAQ(0, 0, b0);
  BARF();

  LOAD_B(b1, 1, BBUF0);
  BARF(); LGKM0();
  MFMAQ(0, 1, b1);
  BARF();

  LOAD_A(1, ABUF0);
  BARF(); LGKM0();
  MFMAQ(1, 1, b1);
  BARF();

  VM0();   // drain: buf1 tile31 (A0,B0,B1 from i=14; A1 from p1) ready
  BARF();
  MFMAQ(1, 0, b0);
  BARF();

  LOAD_A(0, ABUF1); LOAD_B(b0, 0, BBUF1);
  BARF(); LGKM0();
  MFMAQ(0, 0, b0);
  BARF();

  LOAD_B(b1, 1, BBUF1);
  BARF(); LGKM0();
  MFMAQ(0, 1, b1);
  BARF();

  LOAD_A(1, ABUF1);
  BARF(); LGKM0();
  MFMAQ(1, 1, b1);

  MFMAQ(1, 0, b0);   // register-only; no further waits needed

  // ---- epilogue: C[row][col], frag D: col=lane&15, row=(lane>>4)*4+reg ----
  #pragma unroll
  for (int qm = 0; qm < 2; ++qm)
  #pragma unroll
  for (int mi = 0; mi < 4; ++mi)
  #pragma unroll
  for (int qn = 0; qn < 2; ++qn)
  #pragma unroll
  for (int ni = 0; ni < 2; ++ni) {
    f32x4 v = acc[qm][mi][qn][ni];
    int row0 = m0 + qm * 128 + wr64 + mi * 16 + lhi * 4;
    int col  = n0 + qn * 128 + wc32 + ni * 16 + fr;
    #pragma unroll
    for (int r = 0; r < 4; ++r)
      C[(size_t)(row0 + r) * N_CELLS + col] = v[r];
  }
}

// ---------------------------------------------------------------------------
// Fallback f32 GEMM (used only if ws is far too small)
// ---------------------------------------------------------------------------
#define BM 128
#define BN 128
#define BK 16

__global__ __launch_bounds__(256) void recon_gemm_kernel(
    const float* __restrict__ P, const float* __restrict__ V,
    float* __restrict__ C) {
  __shared__ float As[BK][BM + 4];
  __shared__ float Bs[BK][BN + 4];

  const int t  = threadIdx.x;
  const int m0 = blockIdx.y * BM;
  const int n0 = blockIdx.x * BN;
  const int tx = t % 16, ty = t / 16;

  float acc[8][8] = {};

  for (int k0 = 0; k0 < Z_DIM; k0 += BK) {
    {
      int r = t / 4, q = t % 4;
      #pragma unroll
      for (int h = 0; h < 2; ++h) {
        int row = r + 64 * h;
        float4 v = *(const float4*)&P[(size_t)(m0 + row) * Z_DIM + k0 + q * 4];
        As[q * 4 + 0][row] = v.x;
        As[q * 4 + 1][row] = v.y;
        As[q * 4 + 2][row] = v.z;
        As[q * 4 + 3][row] = v.w;
      }
    }
    {
      int kr = t / 32, c4 = t % 32;
      #pragma unroll
      for (int h = 0; h < 2; ++h) {
        int row = kr + 8 * h;
        float4 v = *(const float4*)&V[(size_t)(k0 + row) * N_CELLS + n0 + c4 * 4];
        *(float4*)&Bs[row][c4 * 4] = v;
      }
    }
    __syncthreads();
    #pragma unroll
    for (int kk = 0; kk < BK; ++kk) {
      float aa[8], bb[8];
      *(float4*)&aa[0] = *(const float4*)&As[kk][ty * 8];
      *(float4*)&aa[4] = *(const float4*)&As[kk][ty * 8 + 4];
      *(float4*)&bb[0] = *(const float4*)&Bs[kk][tx * 8];
      *(float4*)&bb[4] = *(const float4*)&Bs[kk][tx * 8 + 4];
      #pragma unroll
      for (int i = 0; i < 8; ++i)
        #pragma unroll
        for (int j = 0; j < 8; ++j)
          acc[i][j] = fmaf(aa[i], bb[j], acc[i][j]);
    }
    __syncthreads();
  }

  #pragma unroll
  for (int i = 0; i < 8; ++i) {
    int row = m0 + ty * 8 + i;
    #pragma unroll
    for (int j4 = 0; j4 < 2; ++j4) {
      float4 v = make_float4(acc[i][j4 * 4 + 0], acc[i][j4 * 4 + 1],
                             acc[i][j4 * 4 + 2], acc[i][j4 * 4 + 3]);
      *(float4*)&C[(size_t)row * N_CELLS + n0 + tx * 8 + j4 * 4] = v;
    }
  }
}

extern "C" void kernel_launch(void* const* d_in, const int* in_sizes, int n_in,
                              void* d_out, int out_size, void* d_ws, size_t ws_size,
                              hipStream_t stream) {
  const float* Q = (const float*)d_in[0];  // 16384 x 128
  const float* K = (const float*)d_in[1];  // 1024 x 128
  const float* V = (const float*)d_in[2];  // 1024 x 4096
  float* recon = (float*)d_out;                          // 16384 x 4096
  float* P     = recon + (size_t)N_GENES * N_CELLS;      // 16384 x 1024

  const size_t pb_elems = (size_t)N_GENES * Z_DIM;   // 16.8M
  const size_t vt_elems = (size_t)Z_DIM * N_CELLS;   // 4.2M
  const size_t q_elems  = (size_t)N_GENES * D_K;     // 2.1M
  const size_t k_elems  = (size_t)Z_DIM * D_K;       // 131K

  const size_t need_mid  = (pb_elems + vt_elems) * sizeof(ushort);
  const size_t need_full = need_mid + 2 * (q_elems + k_elems) * sizeof(ushort);

  if (ws_size >= need_full) {
    ushort* Pb  = (ushort*)d_ws;
    ushort* Vtb = Pb + pb_elems;
    ushort* Qh  = Vtb + vt_elems;
    ushort* Ql  = Qh + q_elems;
    ushort* Kh  = Ql + q_elems;
    ushort* Kl  = Kh + k_elems;
    prep_kernel<<<dim3(NB_HILO + 1024), 256, 0, stream>>>(
        Q, K, V, Qh, Ql, Kh, Kl, Vtb);
    attn_mfma_kernel<<<dim3(N_GENES / 16), 256, 0, stream>>>(
        Qh, Ql, Kh, Kl, P, Pb);
    recon_mfma8_kernel<<<dim3(N_CELLS / 256, N_GENES / 256), 512, 0, stream>>>(
        Pb, Vtb, recon);
  } else if (ws_size >= need_mid) {
    ushort* Pb  = (ushort*)d_ws;
    ushort* Vtb = Pb + pb_elems;
    attn_p_kernel<<<dim3(N_GENES / 8), 256, 0, stream>>>(Q, K, P, Pb);
    recon_mfma8_kernel<<<dim3(N_CELLS / 256, N_GENES / 256), 512, 0, stream>>>(
        Pb, Vtb, recon);
  } else {
    attn_p_kernel<<<dim3(N_GENES / 8), 256, 0, stream>>>(Q, K, P, nullptr);
    recon_gemm_kernel<<<dim3(N_CELLS / BN, N_GENES / BM), 256, 0, stream>>>(
        P, V, recon);
  }
}

// Round 15
// 225.227 us; speedup vs baseline: 6.5097x; 1.0364x over previous
//
#include <hip/hip_runtime.h>
#include <stdint.h>

#define N_GENES 16384
#define Z_DIM   1024
#define D_K     128
#define N_CELLS 4096

typedef __attribute__((ext_vector_type(8))) short bf16x8;
typedef __attribute__((ext_vector_type(4))) float f32x4;

// ---------------------------------------------------------------------------
// JAX threefry2x32 (20 rounds) — verified variant: partitionable, bits1^bits2
// ---------------------------------------------------------------------------
__device__ __forceinline__ uint32_t rotl32(uint32_t x, int r) {
  return (x << r) | (x >> (32 - r));
}

__device__ __forceinline__ void threefry2x32(uint32_t k0, uint32_t k1,
                                             uint32_t& x0, uint32_t& x1) {
  const uint32_t ks2 = k0 ^ k1 ^ 0x1BD11BDAu;
  x0 += k0; x1 += k1;
#define TF_ROUND(r) { x0 += x1; x1 = rotl32(x1, (r)); x1 ^= x0; }
  TF_ROUND(13) TF_ROUND(15) TF_ROUND(26) TF_ROUND(6)
  x0 += k1;  x1 += ks2 + 1u;
  TF_ROUND(17) TF_ROUND(29) TF_ROUND(16) TF_ROUND(24)
  x0 += ks2; x1 += k0 + 2u;
  TF_ROUND(13) TF_ROUND(15) TF_ROUND(26) TF_ROUND(6)
  x0 += k0;  x1 += k1 + 3u;
  TF_ROUND(17) TF_ROUND(29) TF_ROUND(16) TF_ROUND(24)
  x0 += k1;  x1 += ks2 + 4u;
  TF_ROUND(13) TF_ROUND(15) TF_ROUND(26) TF_ROUND(6)
  x0 += ks2; x1 += k0 + 5u;
#undef TF_ROUND
}

__device__ __forceinline__ float gumbel_from(uint32_t n) {
  uint32_t x0 = 0u, x1 = n;   // counter = (hi, lo) of uint64 flat index
  threefry2x32(0u, 42u, x0, x1);
  uint32_t bits = x0 ^ x1;    // partitionable sub-64-bit fold  (R3-verified)
  float f = __uint_as_float((bits >> 9) | 0x3F800000u) - 1.0f;
  const float tiny = 1.17549435082228751e-38f;
  float u = fmaxf(tiny, f + tiny);
  return -logf(-logf(u));
}

__device__ __forceinline__ ushort f32_to_bf16(float x) {
  uint32_t u = __float_as_uint(x);
  uint32_t r = (u + 0x7FFFu + ((u >> 16) & 1u)) >> 16;  // RNE
  return (ushort)r;
}

__device__ __forceinline__ float bf16_to_f32(ushort h) {
  return __uint_as_float(((uint32_t)h) << 16);
}

__device__ __forceinline__ void gload_lds16(const void* g, void* l) {
  __builtin_amdgcn_global_load_lds(
      (const __attribute__((address_space(1))) unsigned int*)g,
      (__attribute__((address_space(3))) unsigned int*)l, 16, 0, 0);
}

// ---------------------------------------------------------------------------
// Kernel P: fused prep (R8-retained). Blocks [0, NB_HILO) do hi/lo split of
// Q then K; blocks [NB_HILO, +1024) transpose+convert V -> Vt bf16.
// ---------------------------------------------------------------------------
#define HILO_Q_N4 (N_GENES * D_K / 4)            // 524288
#define HILO_K_N4 (Z_DIM * D_K / 4)              // 32768
#define NB_HILO   ((HILO_Q_N4 + HILO_K_N4) / 256)  // 2176

__global__ __launch_bounds__(256) void prep_kernel(
    const float* __restrict__ Q, const float* __restrict__ K,
    const float* __restrict__ V,
    ushort* __restrict__ Qh, ushort* __restrict__ Ql,
    ushort* __restrict__ Kh, ushort* __restrict__ Kl,
    ushort* __restrict__ Vt) {
  const int b = blockIdx.x;
  const int t = threadIdx.x;

  if (b < NB_HILO) {
    int i = b * 256 + t;
    const float* src; ushort* hi; ushort* lo;
    if (i < HILO_Q_N4) { src = Q; hi = Qh; lo = Ql; }
    else { i -= HILO_Q_N4; src = K; hi = Kh; lo = Kl; }
    float4 v = ((const float4*)src)[i];
    ushort4 h, l;
    h.x = f32_to_bf16(v.x); l.x = f32_to_bf16(v.x - bf16_to_f32(h.x));
    h.y = f32_to_bf16(v.y); l.y = f32_to_bf16(v.y - bf16_to_f32(h.y));
    h.z = f32_to_bf16(v.z); l.z = f32_to_bf16(v.z - bf16_to_f32(h.z));
    h.w = f32_to_bf16(v.w); l.w = f32_to_bf16(v.w - bf16_to_f32(h.w));
    ((ushort4*)hi)[i] = h;
    ((ushort4*)lo)[i] = l;
    return;
  }

  // V transpose: vb in [0, 1024) -> 64x64 tile
  __shared__ ushort tile[64][68];
  const int vb = b - NB_HILO;
  const int n0 = (vb & 63) * 64;   // cell block
  const int k0 = (vb >> 6) * 64;   // z block

  #pragma unroll
  for (int j = 0; j < 4; ++j) {
    int e = j * 1024 + t * 4;
    int r = e >> 6, c = e & 63;
    float4 v = *(const float4*)&V[(size_t)(k0 + r) * N_CELLS + n0 + c];
    tile[r][c + 0] = f32_to_bf16(v.x);
    tile[r][c + 1] = f32_to_bf16(v.y);
    tile[r][c + 2] = f32_to_bf16(v.z);
    tile[r][c + 3] = f32_to_bf16(v.w);
  }
  __syncthreads();
  #pragma unroll
  for (int j = 0; j < 4; ++j) {
    int u = j * 256 + t;
    int n = u >> 4, kb = (u & 15) * 4;
    ushort4 o;
    o.x = tile[kb + 0][n]; o.y = tile[kb + 1][n];
    o.z = tile[kb + 2][n]; o.w = tile[kb + 3][n];
    *(ushort4*)&Vt[(size_t)(n0 + n) * Z_DIM + k0 + kb] = o;
  }
}

// ---------------------------------------------------------------------------
// Kernel A (MFMA): scores via split-bf16 3-pass MFMA + gumbel-softmax.
// (R7-verified) 16 genes/block, 4 waves; K chunks double-buffered, swizzled.
// ---------------------------------------------------------------------------
__global__ __launch_bounds__(256) void attn_mfma_kernel(
    const ushort* __restrict__ Qh, const ushort* __restrict__ Ql,
    const ushort* __restrict__ Kh, const ushort* __restrict__ Kl,
    float* __restrict__ P, ushort* __restrict__ Pb) {
  __shared__ __attribute__((aligned(16))) ushort qsm[2][16][128];      // [h/l]
  __shared__ __attribute__((aligned(16))) ushort ksm[2][2][64][128];   // [buf][h/l]
  __shared__ float redmax[4][16];
  __shared__ float redsum[4][16];

  const int t    = threadIdx.x;
  const int g0   = blockIdx.x * 16;
  const int wave = t >> 6, lane = t & 63;
  const int fr   = lane & 15, lhi = lane >> 4;

  {
    int un = t, row = un >> 4, usrc = (un & 15) ^ (row & 7);
    gload_lds16(Qh + (size_t)(g0 + row) * D_K + usrc * 8, &qsm[0][0][0] + un * 8);
    gload_lds16(Ql + (size_t)(g0 + row) * D_K + usrc * 8, &qsm[1][0][0] + un * 8);
  }

#define KSTAGE(buf, zc) do {                                                  \
    _Pragma("unroll") for (int j_ = 0; j_ < 4; ++j_) {                        \
      int un_ = j_ * 256 + t, row_ = un_ >> 4;                                \
      int us_ = (un_ & 15) ^ (row_ & 7);                                      \
      gload_lds16(Kh + (size_t)((zc) + row_) * D_K + us_ * 8,                 \
                  &ksm[buf][0][0][0] + un_ * 8);                              \
      gload_lds16(Kl + (size_t)((zc) + row_) * D_K + us_ * 8,                 \
                  &ksm[buf][1][0][0] + un_ * 8);                              \
    } } while (0)

  KSTAGE(0, 0);
  __syncthreads();

  bf16x8 ah[4], al[4];
  #pragma unroll
  for (int ks = 0; ks < 4; ++ks) {
    int q = (ks * 4 + lhi) ^ (fr & 7);
    ah[ks] = *(const bf16x8*)(&qsm[0][fr][0] + q * 8);
    al[ks] = *(const bf16x8*)(&qsm[1][fr][0] + q * 8);
  }

  f32x4 acc[16] = {};
  const int rowk = wave * 16 + fr;

  #pragma unroll
  for (int c = 0; c < 16; ++c) {
    if (c < 15) KSTAGE((c + 1) & 1, (c + 1) * 64);
    const ushort* kbh = &ksm[c & 1][0][0][0];
    const ushort* kbl = &ksm[c & 1][1][0][0];
    #pragma unroll
    for (int ks = 0; ks < 4; ++ks) {
      int q = (ks * 4 + lhi) ^ (fr & 7);
      bf16x8 bh = *(const bf16x8*)(kbh + rowk * 128 + q * 8);
      bf16x8 bl = *(const bf16x8*)(kbl + rowk * 128 + q * 8);
      acc[c] = __builtin_amdgcn_mfma_f32_16x16x32_bf16(ah[ks], bh, acc[c], 0, 0, 0);
      acc[c] = __builtin_amdgcn_mfma_f32_16x16x32_bf16(ah[ks], bl, acc[c], 0, 0, 0);
      acc[c] = __builtin_amdgcn_mfma_f32_16x16x32_bf16(al[ks], bh, acc[c], 0, 0, 0);
    }
    __syncthreads();
  }
#undef KSTAGE

  const float scale = 0.08838834764831845f;  // 1/sqrt(128)

  #pragma unroll
  for (int c = 0; c < 16; ++c) {
    #pragma unroll
    for (int r = 0; r < 4; ++r) {
      uint32_t gene = (uint32_t)(g0 + lhi * 4 + r);
      uint32_t z    = (uint32_t)(c * 64 + wave * 16 + fr);
      acc[c][r] = fmaf(acc[c][r], scale, gumbel_from(gene * (uint32_t)Z_DIM + z));
    }
  }

  float m[4] = {-INFINITY, -INFINITY, -INFINITY, -INFINITY};
  #pragma unroll
  for (int c = 0; c < 16; ++c)
    #pragma unroll
    for (int r = 0; r < 4; ++r) m[r] = fmaxf(m[r], acc[c][r]);
  #pragma unroll
  for (int off = 1; off <= 8; off <<= 1)
    #pragma unroll
    for (int r = 0; r < 4; ++r) m[r] = fmaxf(m[r], __shfl_xor(m[r], off));
  if (fr == 0) {
    #pragma unroll
    for (int r = 0; r < 4; ++r) redmax[wave][lhi * 4 + r] = m[r];
  }
  __syncthreads();
  #pragma unroll
  for (int r = 0; r < 4; ++r) {
    int g = lhi * 4 + r;
    m[r] = fmaxf(fmaxf(redmax[0][g], redmax[1][g]),
                 fmaxf(redmax[2][g], redmax[3][g]));
  }

  float sum[4] = {0.f, 0.f, 0.f, 0.f};
  #pragma unroll
  for (int c = 0; c < 16; ++c)
    #pragma unroll
    for (int r = 0; r < 4; ++r) {
      acc[c][r] = expf(acc[c][r] - m[r]);
      sum[r] += acc[c][r];
    }
  #pragma unroll
  for (int off = 1; off <= 8; off <<= 1)
    #pragma unroll
    for (int r = 0; r < 4; ++r) sum[r] += __shfl_xor(sum[r], off);
  if (fr == 0) {
    #pragma unroll
    for (int r = 0; r < 4; ++r) redsum[wave][lhi * 4 + r] = sum[r];
  }
  __syncthreads();
  float inv[4];
  #pragma unroll
  for (int r = 0; r < 4; ++r) {
    int g = lhi * 4 + r;
    inv[r] = 1.0f / (redsum[0][g] + redsum[1][g] + redsum[2][g] + redsum[3][g]);
  }

  #pragma unroll
  for (int c = 0; c < 16; ++c)
    #pragma unroll
    for (int r = 0; r < 4; ++r) {
      float p = acc[c][r] * inv[r];
      size_t idx = (size_t)(g0 + lhi * 4 + r) * Z_DIM + c * 64 + wave * 16 + fr;
      P[idx] = p;
      Pb[idx] = f32_to_bf16(p);
    }
}

// ---------------------------------------------------------------------------
// Kernel A-fallback (f32 VALU, R3-verified) — used only if ws too small.
// ---------------------------------------------------------------------------
__global__ __launch_bounds__(256) void attn_p_kernel(
    const float* __restrict__ Q, const float* __restrict__ K,
    float* __restrict__ P, ushort* __restrict__ Pb) {
  __shared__ float  qs[8][128];
  __shared__ float4 kk4[64][32];

  const int t    = threadIdx.x;
  const int g0   = blockIdx.x * 8;
  const int wave = t >> 6, lane = t & 63;

  {
    int r = t / 32, c4 = t % 32;
    *(float4*)&qs[r][c4 * 4] =
        *(const float4*)&Q[(size_t)(g0 + r) * D_K + c4 * 4];
  }

  const int r0 = wave * 2, r1 = wave * 2 + 1;
  float sA[16], sB[16];

  for (int c = 0; c < 16; ++c) {
    const int zc = c * 64;
    __syncthreads();
    #pragma unroll
    for (int i = 0; i < 8; ++i) {
      int fidx = t + 256 * i;
      int zr = fidx / 32, c4 = fidx % 32;
      float4 v = *(const float4*)&K[(size_t)(zc + zr) * D_K + c4 * 4];
      kk4[zr][c4 ^ (zr & 31)] = v;
    }
    __syncthreads();
    float s0 = 0.f, s1 = 0.f;
    #pragma unroll
    for (int d4 = 0; d4 < 32; ++d4) {
      float4 kv = kk4[lane][d4 ^ (lane & 31)];
      float4 q0 = *(const float4*)&qs[r0][d4 * 4];
      float4 q1 = *(const float4*)&qs[r1][d4 * 4];
      s0 = fmaf(q0.x, kv.x, s0); s0 = fmaf(q0.y, kv.y, s0);
      s0 = fmaf(q0.z, kv.z, s0); s0 = fmaf(q0.w, kv.w, s0);
      s1 = fmaf(q1.x, kv.x, s1); s1 = fmaf(q1.y, kv.y, s1);
      s1 = fmaf(q1.z, kv.z, s1); s1 = fmaf(q1.w, kv.w, s1);
    }
    sA[c] = s0; sB[c] = s1;
  }

  const float scale = 0.08838834764831845f;

  {
    float s[16]; float mx = -INFINITY;
    #pragma unroll
    for (int i = 0; i < 16; ++i) {
      uint32_t n = (uint32_t)((g0 + r0) * Z_DIM + 64 * i + lane);
      s[i] = fmaf(sA[i], scale, gumbel_from(n));
      mx = fmaxf(mx, s[i]);
    }
    #pragma unroll
    for (int off = 32; off; off >>= 1) mx = fmaxf(mx, __shfl_xor(mx, off));
    float sum = 0.f;
    #pragma unroll
    for (int i = 0; i < 16; ++i) { s[i] = expf(s[i] - mx); sum += s[i]; }
    #pragma unroll
    for (int off = 32; off; off >>= 1) sum += __shfl_xor(sum, off);
    #pragma unroll
    for (int i = 0; i < 16; ++i) {
      size_t idx = (size_t)(g0 + r0) * Z_DIM + 64 * i + lane;
      float p = s[i] / sum;
      P[idx] = p;
      if (Pb) Pb[idx] = f32_to_bf16(p);
    }
  }
  {
    float s[16]; float mx = -INFINITY;
    #pragma unroll
    for (int i = 0; i < 16; ++i) {
      uint32_t n = (uint32_t)((g0 + r1) * Z_DIM + 64 * i + lane);
      s[i] = fmaf(sB[i], scale, gumbel_from(n));
      mx = fmaxf(mx, s[i]);
    }
    #pragma unroll
    for (int off = 32; off; off >>= 1) mx = fmaxf(mx, __shfl_xor(mx, off));
    float sum = 0.f;
    #pragma unroll
    for (int i = 0; i < 16; ++i) { s[i] = expf(s[i] - mx); sum += s[i]; }
    #pragma unroll
    for (int off = 32; off; off >>= 1) sum += __shfl_xor(sum, off);
    #pragma unroll
    for (int i = 0; i < 16; ++i) {
      size_t idx = (size_t)(g0 + r1) * Z_DIM + 64 * i + lane;
      float p = s[i] / sum;
      P[idx] = p;
      if (Pb) Pb[idx] = f32_to_bf16(p);
    }
  }
}

// ---------------------------------------------------------------------------
// Kernel G: 256x256x(BK=64) 8-phase pipelined bf16 MFMA GEMM.
// R11-verified configuration (best: recon ~170 us, total 225.6 us):
// 2D grid, plain stores, peeled last iteration (no junk wrap stages).
// Post-mortems: nt-stores +25us (write amplification); persistent grid +40us
// (XCD L2 thrash); BK=32 @2blk/CU +8us (2x barrier count). Do not re-roll.
// ---------------------------------------------------------------------------
#define ABUF0 0
#define BBUF0 32768
#define ABUF1 65536
#define BBUF1 98304

__global__ __launch_bounds__(512, 2) void recon_mfma8_kernel(
    const ushort* __restrict__ Pb, const ushort* __restrict__ Vt,
    float* __restrict__ C) {
  __shared__ __attribute__((aligned(16))) char smem[131072];

  const int t    = threadIdx.x;
  const int m0   = blockIdx.y * 256;
  const int n0   = blockIdx.x * 256;
  const int wave = t >> 6, lane = t & 63;
  const int wr64 = (wave >> 2) * 64;
  const int wc32 = (wave & 3) * 32;
  const int fr   = lane & 15, lhi = lane >> 4;
  const int ul8  = ((t & 7) ^ ((t >> 3) & 7)) * 8;

#define STAGE(srcP, rowb, ldsbase, tile) do {                                 \
    size_t gb = (size_t)(rowb) * Z_DIM + (size_t)(tile) * 64 + ul8;           \
    _Pragma("unroll")                                                         \
    for (int j_ = 0; j_ < 2; ++j_) {                                          \
      int un_ = j_ * 512 + t;                                                 \
      gload_lds16(srcP + gb + (size_t)(un_ >> 3) * Z_DIM,                     \
                  smem + (ldsbase) + un_ * 16);                               \
    } } while (0)

#define LOAD_A(qm, abase) do {                                                \
    _Pragma("unroll") for (int mi_ = 0; mi_ < 4; ++mi_)                       \
    _Pragma("unroll") for (int ks_ = 0; ks_ < 2; ++ks_) {                     \
      int row_ = (qm) * 128 + wr64 + mi_ * 16 + fr;                           \
      int un_  = (ks_ * 4 + lhi) ^ (fr & 7);                                  \
      a[mi_][ks_] = *(const bf16x8*)(smem + (abase) + row_ * 128 + un_ * 16); \
    } } while (0)

#define LOAD_B(dst, qn, bbase) do {                                           \
    _Pragma("unroll") for (int ni_ = 0; ni_ < 2; ++ni_)                       \
    _Pragma("unroll") for (int ks_ = 0; ks_ < 2; ++ks_) {                     \
      int row_ = (qn) * 128 + wc32 + ni_ * 16 + fr;                           \
      int un_  = (ks_ * 4 + lhi) ^ (fr & 7);                                  \
      dst[ni_][ks_] = *(const bf16x8*)(smem + (bbase) + row_ * 128 + un_ * 16);\
    } } while (0)

#define MFMAQ(qm, qn, bb) do {                                                \
    __builtin_amdgcn_s_setprio(1);                                            \
    _Pragma("unroll") for (int mi_ = 0; mi_ < 4; ++mi_)                       \
    _Pragma("unroll") for (int ni_ = 0; ni_ < 2; ++ni_)                       \
    _Pragma("unroll") for (int ks_ = 0; ks_ < 2; ++ks_)                       \
      acc[qm][mi_][qn][ni_] = __builtin_amdgcn_mfma_f32_16x16x32_bf16(        \
          a[mi_][ks_], bb[ni_][ks_], acc[qm][mi_][qn][ni_], 0, 0, 0);         \
    __builtin_amdgcn_s_setprio(0);                                            \
  } while (0)

#define BARF()  do { __builtin_amdgcn_s_barrier();                            \
                     __builtin_amdgcn_sched_barrier(0); } while (0)
#define LGKM0() do { asm volatile("s_waitcnt lgkmcnt(0)" ::: "memory");       \
                     __builtin_amdgcn_sched_barrier(0); } while (0)
#define VM6()   do { asm volatile("s_waitcnt vmcnt(6)" ::: "memory");         \
                     __builtin_amdgcn_sched_barrier(0); } while (0)
#define VM0()   do { asm volatile("s_waitcnt vmcnt(0)" ::: "memory");         \
                     __builtin_amdgcn_sched_barrier(0); } while (0)

  f32x4 acc[2][4][2][2] = {};
  bf16x8 a[4][2], b0[2][2], b1[2][2];

  // ---- prologue: tile0 -> buf0 (4 halves); tile1 -> buf1 (A0,B0,B1) ----
  STAGE(Pb, m0,       ABUF0,         0);
  STAGE(Pb, m0 + 128, ABUF0 + 16384, 0);
  STAGE(Vt, n0,       BBUF0,         0);
  STAGE(Vt, n0 + 128, BBUF0 + 16384, 0);
  STAGE(Pb, m0,       ABUF1,         1);
  STAGE(Vt, n0,       BBUF1,         1);
  STAGE(Vt, n0 + 128, BBUF1 + 16384, 1);
  VM6();
  BARF();

  // ---- main loop: iterations 0..6 (no wrap fires) ----
  for (int i = 0; i < 7; ++i) {
    const int t1 = 2 * i + 1;
    const int t2 = 2 * i + 2;
    const int t3 = 2 * i + 3;

    LOAD_A(0, ABUF0); LOAD_B(b0, 0, BBUF0);
    STAGE(Pb, m0 + 128, ABUF1 + 16384, t1);
    BARF(); LGKM0();
    MFMAQ(0, 0, b0);
    BARF();

    LOAD_B(b1, 1, BBUF0);
    STAGE(Pb, m0, ABUF0, t2);
    BARF(); LGKM0();
    MFMAQ(0, 1, b1);
    BARF();

    LOAD_A(1, ABUF0);
    STAGE(Vt, n0, BBUF0, t2);
    BARF(); LGKM0();
    MFMAQ(1, 1, b1);
    BARF();

    STAGE(Vt, n0 + 128, BBUF0 + 16384, t2);
    VM6();
    BARF();
    MFMAQ(1, 0, b0);
    BARF();

    LOAD_A(0, ABUF1); LOAD_B(b0, 0, BBUF1);
    STAGE(Pb, m0 + 128, ABUF0 + 16384, t2);
    BARF(); LGKM0();
    MFMAQ(0, 0, b0);
    BARF();

    LOAD_B(b1, 1, BBUF1);
    STAGE(Pb, m0, ABUF1, t3);
    BARF(); LGKM0();
    MFMAQ(0, 1, b1);
    BARF();

    LOAD_A(1, ABUF1);
    STAGE(Vt, n0, BBUF1, t3);
    BARF(); LGKM0();
    MFMAQ(1, 1, b1);
    BARF();

    STAGE(Vt, n0 + 128, BBUF1 + 16384, t3);
    VM6();
    BARF();
    MFMAQ(1, 0, b0);
    BARF();
  }

  // ---- peeled i=7: no junk prefetch; p1's t1=15 stage is valid & kept ----
  LOAD_A(0, ABUF0); LOAD_B(b0, 0, BBUF0);
  STAGE(Pb, m0 + 128, ABUF1 + 16384, 15);
  BARF(); LGKM0();
  MFMAQ(0, 0, b0);
  BARF();

  LOAD_B(b1, 1, BBUF0);
  BARF(); LGKM0();
  MFMAQ(0, 1, b1);
  BARF();

  LOAD_A(1, ABUF0);
  BARF(); LGKM0();
  MFMAQ(1, 1, b1);
  BARF();

  VM0();   // drain everything: buf1 tile15 fully landed
  BARF();
  MFMAQ(1, 0, b0);
  BARF();

  LOAD_A(0, ABUF1); LOAD_B(b0, 0, BBUF1);
  BARF(); LGKM0();
  MFMAQ(0, 0, b0);
  BARF();

  LOAD_B(b1, 1, BBUF1);
  BARF(); LGKM0();
  MFMAQ(0, 1, b1);
  BARF();

  LOAD_A(1, ABUF1);
  BARF(); LGKM0();
  MFMAQ(1, 1, b1);

  MFMAQ(1, 0, b0);   // register-only; no further waits needed

  // ---- epilogue: C[row][col], frag D: col=lane&15, row=(lane>>4)*4+reg ----
  #pragma unroll
  for (int qm = 0; qm < 2; ++qm)
  #pragma unroll
  for (int mi = 0; mi < 4; ++mi)
  #pragma unroll
  for (int qn = 0; qn < 2; ++qn)
  #pragma unroll
  for (int ni = 0; ni < 2; ++ni) {
    f32x4 v = acc[qm][mi][qn][ni];
    int row0 = m0 + qm * 128 + wr64 + mi * 16 + lhi * 4;
    int col  = n0 + qn * 128 + wc32 + ni * 16 + fr;
    #pragma unroll
    for (int r = 0; r < 4; ++r)
      C[(size_t)(row0 + r) * N_CELLS + col] = v[r];
  }
}

// ---------------------------------------------------------------------------
// Fallback f32 GEMM (used only if ws is far too small)
// ---------------------------------------------------------------------------
#define BM 128
#define BN 128
#define BK 16

__global__ __launch_bounds__(256) void recon_gemm_kernel(
    const float* __restrict__ P, const float* __restrict__ V,
    float* __restrict__ C) {
  __shared__ float As[BK][BM + 4];
  __shared__ float Bs[BK][BN + 4];

  const int t  = threadIdx.x;
  const int m0 = blockIdx.y * BM;
  const int n0 = blockIdx.x * BN;
  const int tx = t % 16, ty = t / 16;

  float acc[8][8] = {};

  for (int k0 = 0; k0 < Z_DIM; k0 += BK) {
    {
      int r = t / 4, q = t % 4;
      #pragma unroll
      for (int h = 0; h < 2; ++h) {
        int row = r + 64 * h;
        float4 v = *(const float4*)&P[(size_t)(m0 + row) * Z_DIM + k0 + q * 4];
        As[q * 4 + 0][row] = v.x;
        As[q * 4 + 1][row] = v.y;
        As[q * 4 + 2][row] = v.z;
        As[q * 4 + 3][row] = v.w;
      }
    }
    {
      int kr = t / 32, c4 = t % 32;
      #pragma unroll
      for (int h = 0; h < 2; ++h) {
        int row = kr + 8 * h;
        float4 v = *(const float4*)&V[(size_t)(k0 + row) * N_CELLS + n0 + c4 * 4];
        *(float4*)&Bs[row][c4 * 4] = v;
      }
    }
    __syncthreads();
    #pragma unroll
    for (int kk = 0; kk < BK; ++kk) {
      float aa[8], bb[8];
      *(float4*)&aa[0] = *(const float4*)&As[kk][ty * 8];
      *(float4*)&aa[4] = *(const float4*)&As[kk][ty * 8 + 4];
      *(float4*)&bb[0] = *(const float4*)&Bs[kk][tx * 8];
      *(float4*)&bb[4] = *(const float4*)&Bs[kk][tx * 8 + 4];
      #pragma unroll
      for (int i = 0; i < 8; ++i)
        #pragma unroll
        for (int j = 0; j < 8; ++j)
          acc[i][j] = fmaf(aa[i], bb[j], acc[i][j]);
    }
    __syncthreads();
  }

  #pragma unroll
  for (int i = 0; i < 8; ++i) {
    int row = m0 + ty * 8 + i;
    #pragma unroll
    for (int j4 = 0; j4 < 2; ++j4) {
      float4 v = make_float4(acc[i][j4 * 4 + 0], acc[i][j4 * 4 + 1],
                             acc[i][j4 * 4 + 2], acc[i][j4 * 4 + 3]);
      *(float4*)&C[(size_t)row * N_CELLS + n0 + tx * 8 + j4 * 4] = v;
    }
  }
}

extern "C" void kernel_launch(void* const* d_in, const int* in_sizes, int n_in,
                              void* d_out, int out_size, void* d_ws, size_t ws_size,
                              hipStream_t stream) {
  const float* Q = (const float*)d_in[0];  // 16384 x 128
  const float* K = (const float*)d_in[1];  // 1024 x 128
  const float* V = (const float*)d_in[2];  // 1024 x 4096
  float* recon = (float*)d_out;                          // 16384 x 4096
  float* P     = recon + (size_t)N_GENES * N_CELLS;      // 16384 x 1024

  const size_t pb_elems = (size_t)N_GENES * Z_DIM;   // 16.8M
  const size_t vt_elems = (size_t)Z_DIM * N_CELLS;   // 4.2M
  const size_t q_elems  = (size_t)N_GENES * D_K;     // 2.1M
  const size_t k_elems  = (size_t)Z_DIM * D_K;       // 131K

  const size_t need_mid  = (pb_elems + vt_elems) * sizeof(ushort);
  const size_t need_full = need_mid + 2 * (q_elems + k_elems) * sizeof(ushort);

  if (ws_size >= need_full) {
    ushort* Pb  = (ushort*)d_ws;
    ushort* Vtb = Pb + pb_elems;
    ushort* Qh  = Vtb + vt_elems;
    ushort* Ql  = Qh + q_elems;
    ushort* Kh  = Ql + q_elems;
    ushort* Kl  = Kh + k_elems;
    prep_kernel<<<dim3(NB_HILO + 1024), 256, 0, stream>>>(
        Q, K, V, Qh, Ql, Kh, Kl, Vtb);
    attn_mfma_kernel<<<dim3(N_GENES / 16), 256, 0, stream>>>(
        Qh, Ql, Kh, Kl, P, Pb);
    recon_mfma8_kernel<<<dim3(N_CELLS / 256, N_GENES / 256), 512, 0, stream>>>(
        Pb, Vtb, recon);
  } else if (ws_size >= need_mid) {
    ushort* Pb  = (ushort*)d_ws;
    ushort* Vtb = Pb + pb_elems;
    attn_p_kernel<<<dim3(N_GENES / 8), 256, 0, stream>>>(Q, K, P, Pb);
    recon_mfma8_kernel<<<dim3(N_CELLS / 256, N_GENES / 256), 512, 0, stream>>>(
        Pb, Vtb, recon);
  } else {
    attn_p_kernel<<<dim3(N_GENES / 8), 256, 0, stream>>>(Q, K, P, nullptr);
    recon_gemm_kernel<<<dim3(N_CELLS / BN, N_GENES / BM), 256, 0, stream>>>(
        P, V, recon);
  }
}